// Round 5
// baseline (164.266 us; speedup 1.0000x reference)
//
#include <hip/hip_runtime.h>
#include <math.h>

#define DIM 512
#define NP  64
#define TAU 1e-5f          // gap34 flag threshold (cosine units)
#define LISTCAP 8192
#define RFB 128

// workspace layout (bytes)
#define WS_PTRAW 0          // float[512][64] raw transposed protos   (131072)
#define WS_PTN   131072     // float[512][64] normalized transposed   (131072)
#define WS_INV64 262144     // double[64]                             (512)
#define WS_CNT   262656     // int                                    (4)
#define WS_LIST  262784     // int[LISTCAP]                           (32768)

// ---------------------------------------------------------------------------
// insert helpers (descending top-k with index tracking)
// ---------------------------------------------------------------------------
__device__ __forceinline__ void ins4f(float v, int idx, float& v0, float& v1,
                                      float& v2, float& v3, int& j0, int& j1,
                                      int& j2, int& j3) {
  const bool b0 = v > v0, b1 = v > v1, b2 = v > v2, b3 = v > v3;
  v3 = b2 ? v2 : (b3 ? v : v3);  j3 = b2 ? j2 : (b3 ? idx : j3);
  v2 = b1 ? v1 : (b2 ? v : v2);  j2 = b1 ? j1 : (b2 ? idx : j2);
  v1 = b0 ? v0 : (b1 ? v : v1);  j1 = b0 ? j0 : (b1 ? idx : j1);
  v0 = b0 ? v  : v0;             j0 = b0 ? idx : j0;
}

__device__ __forceinline__ void ins3d(double v, int idx, double& b0, double& b1,
                                      double& b2, int& k0, int& k1, int& k2) {
  const bool c0 = v > b0, c1 = v > b1, c2 = v > b2;
  b2 = c1 ? b1 : (c2 ? v : b2);  k2 = c1 ? k1 : (c2 ? idx : k2);
  b1 = c0 ? b0 : (c1 ? v : b1);  k1 = c0 ? k0 : (c1 ? idx : k1);
  b0 = c0 ? v  : b0;             k0 = c0 ? idx : k0;
}

// ---------------------------------------------------------------------------
// Kernel 1: transpose protos -> ptw[k][p] (raw) + ptn[k][p] (normalized);
// fp64 inverse norms; zero the flag count. One wave per prototype.
// ---------------------------------------------------------------------------
__global__ __launch_bounds__(256) void prep_kernel(
    const float* __restrict__ protos, float* __restrict__ ptw,
    float* __restrict__ ptn, double* __restrict__ inv64,
    int* __restrict__ cnt) {
  if (blockIdx.x == 0 && threadIdx.x == 0) *cnt = 0;
  const int p = (blockIdx.x * 256 + threadIdx.x) >> 6;
  const int lane = threadIdx.x & 63;
  if (p >= NP) return;
  const float4* pr = (const float4*)(protos + (size_t)p * DIM);
  const float4 a = pr[lane * 2];
  const float4 b = pr[lane * 2 + 1];
  double ss = (double)a.x * a.x + (double)a.y * a.y + (double)a.z * a.z +
              (double)a.w * a.w + (double)b.x * b.x + (double)b.y * b.y +
              (double)b.z * b.z + (double)b.w * b.w;
#pragma unroll
  for (int m = 1; m < 64; m <<= 1) ss += __shfl_xor(ss, m);
  const double inv = 1.0 / fmax(sqrt(ss), 1e-12);
  if (lane == 0) inv64[p] = inv;
  const float v[8] = {a.x, a.y, a.z, a.w, b.x, b.y, b.z, b.w};
#pragma unroll
  for (int e = 0; e < 8; ++e) {
    const size_t o = (size_t)(lane * 8 + e) * NP + p;
    ptw[o] = v[e];
    ptn[o] = (float)((double)v[e] * inv);
  }
}

// ---------------------------------------------------------------------------
// Kernel 2: single-wave blocks (64 thr). 64 rows x 64 protos per block,
// 8x8 register tile per lane. Double-buffered LDS, ZERO barriers
// (single-wave in-order DS). Fused top-4 select + softmax + gather.
// ---------------------------------------------------------------------------
__global__ __launch_bounds__(64, 1) void sim_kernel(
    const float* __restrict__ query, const float* __restrict__ protos,
    const float* __restrict__ ptn, float* __restrict__ out,
    int* __restrict__ cnt, int* __restrict__ list) {
  __shared__ float Ast[2][32][64];   // [buf][k][row]   16 KiB
  __shared__ float Bst[2][32][64];   // [buf][k][proto] 16 KiB
  __shared__ float qiS[64];
  __shared__ float4 wiS[64];

  const int l = threadIdx.x;        // 0..63
  const int pg = l & 7;             // proto group: protos pg*8..pg*8+7
  const int rg = l >> 3;            // row group:   rows  rg*8..rg*8+7
  const int row0 = blockIdx.x * 64;

  const float* aq = query + (size_t)(row0 + l) * DIM;  // lane stages row l
  const float* bq = ptn + l * 4;                       // B stage base
  const int bkw = l >> 4;           // B lds write k-sub
  const int bpw = (l & 15) * 4;     // B lds write proto col

  float acc[8][8] = {};
  float ss = 0.f;

  // ---- prologue: chunk 0 -> buf 0 ----
  {
    float4 ar[8], br[8];
#pragma unroll
    for (int s = 0; s < 8; ++s) ar[s] = *(const float4*)(aq + s * 4);
#pragma unroll
    for (int s = 0; s < 8; ++s) br[s] = *(const float4*)(bq + s * 256);
#pragma unroll
    for (int s = 0; s < 8; ++s) {
      Ast[0][s * 4 + 0][l] = ar[s].x;
      Ast[0][s * 4 + 1][l] = ar[s].y;
      Ast[0][s * 4 + 2][l] = ar[s].z;
      Ast[0][s * 4 + 3][l] = ar[s].w;
      *(float4*)&Bst[0][s * 4 + bkw][bpw] = br[s];
      ss += ar[s].x * ar[s].x + ar[s].y * ar[s].y + ar[s].z * ar[s].z +
            ar[s].w * ar[s].w;
    }
  }

  // ---- main loop: compute buf, stage next into buf^1 ----
  for (int c = 0; c < 16; ++c) {
    const int buf = c & 1;
    float4 an[8], bn[8];
    if (c < 15) {  // issue next-chunk global loads (latency hidden by FMAs)
#pragma unroll
      for (int s = 0; s < 8; ++s)
        an[s] = *(const float4*)(aq + (c + 1) * 32 + s * 4);
#pragma unroll
      for (int s = 0; s < 8; ++s)
        bn[s] = *(const float4*)(bq + (size_t)(c + 1) * 2048 + s * 256);
    }
    const float* Ab = &Ast[buf][0][rg * 8];
    const float* Bb = &Bst[buf][0][pg * 8];
#pragma unroll 8
    for (int kk = 0; kk < 32; ++kk) {
      const float4 A0 = *(const float4*)(Ab + kk * 64);
      const float4 A1 = *(const float4*)(Ab + kk * 64 + 4);
      const float4 B0 = *(const float4*)(Bb + kk * 64);
      const float4 B1 = *(const float4*)(Bb + kk * 64 + 4);
      const float av[8] = {A0.x, A0.y, A0.z, A0.w, A1.x, A1.y, A1.z, A1.w};
      const float bv[8] = {B0.x, B0.y, B0.z, B0.w, B1.x, B1.y, B1.z, B1.w};
#pragma unroll
      for (int i = 0; i < 8; ++i)
#pragma unroll
        for (int j = 0; j < 8; ++j)
          acc[i][j] = fmaf(av[i], bv[j], acc[i][j]);
    }
    if (c < 15) {  // write staged regs into the other buffer (in-order DS)
      const int nb = buf ^ 1;
#pragma unroll
      for (int s = 0; s < 8; ++s) {
        Ast[nb][s * 4 + 0][l] = an[s].x;
        Ast[nb][s * 4 + 1][l] = an[s].y;
        Ast[nb][s * 4 + 2][l] = an[s].z;
        Ast[nb][s * 4 + 3][l] = an[s].w;
        *(float4*)&Bst[nb][s * 4 + bkw][bpw] = bn[s];
        ss += an[s].x * an[s].x + an[s].y * an[s].y + an[s].z * an[s].z +
              an[s].w * an[s].w;
      }
    }
  }

  // per-row inverse norm (lane == row, exact per-lane sumsq)
  qiS[l] = 1.0f / fmaxf(sqrtf(ss), 1e-12f);

  // ---- selection: top-4 per row; acc already = dot(q, p_normalized) ----
#pragma unroll
  for (int i = 0; i < 8; ++i) {
    float v0 = -1e30f, v1 = -1e30f, v2 = -1e30f, v3 = -1e30f;
    int j0 = 0, j1 = 0, j2 = 0, j3 = 0;
#pragma unroll
    for (int j = 0; j < 8; ++j)
      ins4f(acc[i][j], pg * 8 + j, v0, v1, v2, v3, j0, j1, j2, j3);
#pragma unroll
    for (int m = 1; m <= 4; m <<= 1) {   // butterfly across the 8 pg lanes
      const float p0 = __shfl_xor(v0, m), p1 = __shfl_xor(v1, m);
      const float p2 = __shfl_xor(v2, m), p3 = __shfl_xor(v3, m);
      const int q0 = __shfl_xor(j0, m), q1 = __shfl_xor(j1, m);
      const int q2 = __shfl_xor(j2, m), q3 = __shfl_xor(j3, m);
      ins4f(p0, q0, v0, v1, v2, v3, j0, j1, j2, j3);
      ins4f(p1, q1, v0, v1, v2, v3, j0, j1, j2, j3);
      ins4f(p2, q2, v0, v1, v2, v3, j0, j1, j2, j3);
      ins4f(p3, q3, v0, v1, v2, v3, j0, j1, j2, j3);
    }
    if (pg == 0) {
      const int row = rg * 8 + i;
      const float qi = qiS[row];
      const float s0 = v0 * qi, s1 = v1 * qi, s2 = v2 * qi, s3 = v3 * qi;
      const float e1 = expf(s1 - s0), e2 = expf(s2 - s0);
      const float inv = 1.0f / (1.0f + e1 + e2);
      wiS[row] = make_float4(inv, e1 * inv, e2 * inv,
                             __int_as_float(j0 | (j1 << 6) | (j2 << 12)));
      if (s2 - s3 < TAU) {
        const int pos = atomicAdd(cnt, 1);
        if (pos < LISTCAP) list[pos] = row0 + row;
      }
    }
  }

  // ---- epilogue: weighted gather, coalesced 1 KB accesses ----
#pragma unroll 2
  for (int r = 0; r < 64; ++r) {
    const float4 wi = wiS[r];
    const int pack = __float_as_int(wi.w);
    const int i0 = pack & 63, i1 = (pack >> 6) & 63, i2 = (pack >> 12) & 63;
    const float* p0 = protos + (size_t)i0 * DIM;
    const float* p1 = protos + (size_t)i1 * DIM;
    const float* p2 = protos + (size_t)i2 * DIM;
    float* orow = out + (size_t)(row0 + r) * DIM;
#pragma unroll
    for (int h = 0; h < 2; ++h) {
      const int col = h * 256 + l * 4;
      const float4 x = *(const float4*)(p0 + col);
      const float4 y = *(const float4*)(p1 + col);
      const float4 z = *(const float4*)(p2 + col);
      float4 res;
      res.x = wi.x * x.x + wi.y * y.x + wi.z * z.x;
      res.y = wi.x * x.y + wi.y * y.y + wi.z * z.y;
      res.z = wi.x * x.z + wi.y * y.z + wi.z * z.z;
      res.w = wi.x * x.w + wi.y * y.w + wi.z * z.w;
      *(float4*)(orow + col) = res;
    }
  }
}

// ---------------------------------------------------------------------------
// Kernel 3: fp64 refine of compacted near-tie rows. One wave per row.
// ---------------------------------------------------------------------------
__global__ __launch_bounds__(256) void refine_kernel(
    const float* __restrict__ query, const float* __restrict__ protos,
    const float* __restrict__ ptw, const double* __restrict__ inv64,
    const int* __restrict__ cnt, const int* __restrict__ list,
    float* __restrict__ out) {
  const int n = min(*cnt, LISTCAP);
  const int lane = threadIdx.x & 63;
  const int gw = blockIdx.x * 4 + (threadIdx.x >> 6);

  for (int i = gw; i < n; i += RFB * 4) {
    const int row = list[i];
    const float* q = query + (size_t)row * DIM;
    double a0 = 0.0, a1 = 0.0, a2 = 0.0, a3 = 0.0;
    float qs = 0.f;
#pragma unroll 4
    for (int k = 0; k < DIM; k += 4) {
      const float4 qv = *(const float4*)(q + k);
      a0 = fma((double)qv.x, (double)ptw[(size_t)(k + 0) * NP + lane], a0);
      a1 = fma((double)qv.y, (double)ptw[(size_t)(k + 1) * NP + lane], a1);
      a2 = fma((double)qv.z, (double)ptw[(size_t)(k + 2) * NP + lane], a2);
      a3 = fma((double)qv.w, (double)ptw[(size_t)(k + 3) * NP + lane], a3);
      qs += qv.x * qv.x + qv.y * qv.y + qv.z * qv.z + qv.w * qv.w;
    }
    const double sim = (a0 + a1 + a2 + a3) * inv64[lane];

    double b0 = sim, b1 = -1e300, b2 = -1e300;
    int k0 = lane, k1 = 0, k2 = 0;
#pragma unroll
    for (int m = 1; m <= 32; m <<= 1) {
      const double p0 = __shfl_xor(b0, m), p1 = __shfl_xor(b1, m),
                   p2 = __shfl_xor(b2, m);
      const int q0 = __shfl_xor(k0, m), q1 = __shfl_xor(k1, m),
                q2 = __shfl_xor(k2, m);
      ins3d(p0, q0, b0, b1, b2, k0, k1, k2);
      ins3d(p1, q1, b0, b1, b2, k0, k1, k2);
      ins3d(p2, q2, b0, b1, b2, k0, k1, k2);
    }
    const double qi = 1.0 / fmax(sqrt((double)qs), 1e-12);
    const double s0 = b0 * qi, s1 = b1 * qi, s2 = b2 * qi;
    const double e1 = exp(s1 - s0), e2 = exp(s2 - s0);
    const double inv = 1.0 / (1.0 + e1 + e2);
    const double w0 = inv, w1 = e1 * inv, w2 = e2 * inv;
    const float* p0r = protos + (size_t)k0 * DIM;
    const float* p1r = protos + (size_t)k1 * DIM;
    const float* p2r = protos + (size_t)k2 * DIM;
#pragma unroll
    for (int u = 0; u < 2; ++u) {
      const int col = u * 256 + lane * 4;
      const float4 x = *(const float4*)(p0r + col);
      const float4 y = *(const float4*)(p1r + col);
      const float4 z = *(const float4*)(p2r + col);
      float4 res;
      res.x = (float)(w0 * x.x + w1 * y.x + w2 * z.x);
      res.y = (float)(w0 * x.y + w1 * y.y + w2 * z.y);
      res.z = (float)(w0 * x.z + w1 * y.z + w2 * z.z);
      res.w = (float)(w0 * x.w + w1 * y.w + w2 * z.w);
      *(float4*)(out + (size_t)row * DIM + col) = res;
    }
  }
}

extern "C" void kernel_launch(void* const* d_in, const int* in_sizes, int n_in,
                              void* d_out, int out_size, void* d_ws, size_t ws_size,
                              hipStream_t stream) {
  const float* query = (const float*)d_in[0];
  const float* protos = (const float*)d_in[1];
  float* out = (float*)d_out;
  float* ptw = (float*)((char*)d_ws + WS_PTRAW);
  float* ptn = (float*)((char*)d_ws + WS_PTN);
  double* inv64 = (double*)((char*)d_ws + WS_INV64);
  int* cnt = (int*)((char*)d_ws + WS_CNT);
  int* list = (int*)((char*)d_ws + WS_LIST);

  const int nrows = in_sizes[0] / DIM;

  hipLaunchKernelGGL(prep_kernel, dim3(16), dim3(256), 0, stream,
                     protos, ptw, ptn, inv64, cnt);
  hipLaunchKernelGGL(sim_kernel, dim3(nrows / 64), dim3(64), 0, stream,
                     query, protos, ptn, out, cnt, list);
  hipLaunchKernelGGL(refine_kernel, dim3(RFB), dim3(256), 0, stream,
                     query, protos, ptw, inv64, cnt, list, out);
}